// Round 4
// baseline (1127.433 us; speedup 1.0000x reference)
//
#include <hip/hip_runtime.h>
#include <hip/hip_bf16.h>
#include <math.h>

typedef __attribute__((ext_vector_type(8))) short bf16x8;
typedef __attribute__((ext_vector_type(4))) float f32x4;

#define R_TOTAL 8
#define CIN     256
#define COUT    256
#define HH      128
#define WW      128
#define BB      4
#define MTOT    (COUT * R_TOTAL)   // 2048
#define KTAPS   9

#define XSZ  (3 * 130 * 32)        // elems per xs buffer (24.96 KB)

// ---------------------------------------------------------------------------
// async global->LDS, 16B per lane (lane l lands at base + l*16).
// ---------------------------------------------------------------------------
__device__ __forceinline__ void g2l16(void* lds, const void* g) {
    __builtin_amdgcn_global_load_lds(
        (const __attribute__((address_space(1))) unsigned int*)g,
        (__attribute__((address_space(3))) unsigned int*)lds,
        16, 0, 0);
}

// ---------------------------------------------------------------------------
// x (B,C,H,W) fp32 -> xb (B,H,W,C) bf16 (+ one appended zero row).
// ---------------------------------------------------------------------------
__global__ __launch_bounds__(256)
void to_nhwc_bf16(const float* __restrict__ x, __hip_bfloat16* __restrict__ xb) {
    __shared__ __hip_bfloat16 t[32][33];
    const int b  = blockIdx.z;
    const int c0 = blockIdx.y * 32;
    const int p0 = blockIdx.x * 32;
    const int tx = threadIdx.x & 31;
    const int ty = threadIdx.x >> 5;
    const float* xp = x + (size_t)b * CIN * (HH * WW);
    #pragma unroll
    for (int j = 0; j < 4; ++j) {
        int c = ty * 4 + j;
        t[c][tx] = __float2bfloat16(xp[(size_t)(c0 + c) * (HH * WW) + p0 + tx]);
    }
    __syncthreads();
    __hip_bfloat16* op = xb + ((size_t)b * (HH * WW) + p0) * CIN + c0;
    #pragma unroll
    for (int j = 0; j < 4; ++j) {
        int p = ty * 4 + j;
        op[(size_t)p * CIN + tx] = t[tx][p];
    }
}

__global__ __launch_bounds__(256)
void zero_guard_row(__hip_bfloat16* __restrict__ xb) {
    // one shared zero pixel-row at row index BB*HH (WW*CIN elems)
    size_t base = (size_t)BB * HH * WW * CIN;
    int i = blockIdx.x * 256 + threadIdx.x;
    xb[base + i] = __float2bfloat16(0.0f);
}

// ---------------------------------------------------------------------------
// Rotate weights (fp32 math == jax affine_grid/grid_sample, align_corners=F,
// zero pad) -> rwb[m][tap][i] bf16, m = o*8 + r.
// ---------------------------------------------------------------------------
__global__ __launch_bounds__(256)
void rotate_weights_bf16(const float* __restrict__ w, __hip_bfloat16* __restrict__ rwb) {
    const int i = threadIdx.x;
    const int m = blockIdx.x;
    const int o = m >> 3, r = m & 7;

    float ang = 6.283185307179586f * (float)r / 8.0f;
    float cs = cosf(ang), sn = sinf(ang);

    const float* wp = w + ((size_t)o * CIN + i) * 9;
    __hip_bfloat16* op = rwb + (size_t)m * (KTAPS * CIN) + i;

    #pragma unroll
    for (int ky = 0; ky < 3; ++ky) {
        #pragma unroll
        for (int kx = 0; kx < 3; ++kx) {
            float yg = (2.0f * (float)ky + 1.0f) / 3.0f - 1.0f;
            float xg = (2.0f * (float)kx + 1.0f) / 3.0f - 1.0f;
            float xsf = cs * xg - sn * yg;
            float ysf = sn * xg + cs * yg;
            float ix = ((xsf + 1.0f) * 3.0f - 1.0f) * 0.5f;
            float iy = ((ysf + 1.0f) * 3.0f - 1.0f) * 0.5f;
            float ix0f = floorf(ix), iy0f = floorf(iy);
            float wx1 = ix - ix0f,  wy1 = iy - iy0f;
            float wx0 = 1.0f - wx1, wy0 = 1.0f - wy1;
            int ix0 = (int)ix0f, iy0 = (int)iy0f;
            int ix1 = ix0 + 1,   iy1 = iy0 + 1;
            float acc = 0.0f;
            if (iy0 >= 0 && iy0 < 3 && ix0 >= 0 && ix0 < 3) acc += wp[iy0*3+ix0] * (wy0*wx0);
            if (iy0 >= 0 && iy0 < 3 && ix1 >= 0 && ix1 < 3) acc += wp[iy0*3+ix1] * (wy0*wx1);
            if (iy1 >= 0 && iy1 < 3 && ix0 >= 0 && ix0 < 3) acc += wp[iy1*3+ix0] * (wy1*wx0);
            if (iy1 >= 0 && iy1 < 3 && ix1 >= 0 && ix1 < 3) acc += wp[iy1*3+ix1] * (wy1*wx1);
            op[(ky * 3 + kx) * CIN] = __float2bfloat16(acc);
        }
    }
}

// ---------------------------------------------------------------------------
// Main MFMA conv. Block tile 128(M) x 128(N = one image row), 4 waves of
// 64x64, mfma 16x16x32 bf16. K = 8 chunks(32ch) x 9 taps.
// A fragments loaded DIRECTLY global->register (contiguous 16B per lane,
// 3-buffer rotation, prefetch distance 2 taps). X staged in double-buffered
// LDS (only LDS consumer) -> ONE __syncthreads per chunk (144 MFMA/barrier).
// ---------------------------------------------------------------------------
__global__ __launch_bounds__(256)
void rotconv_mfma_kernel(const __hip_bfloat16* __restrict__ xb,
                         const __hip_bfloat16* __restrict__ rwb,
                         float* __restrict__ out) {
    const int tid  = threadIdx.x;
    const int lane = tid & 63;
    const int w    = tid >> 6;
    const int wm   = w >> 1, wn = w & 1;
    const int q    = lane >> 4, lr = lane & 15;

    const int bid = blockIdx.x;
    const int mt  = bid >> 9;          // m-major -> 512 blocks share one A panel
    const int nt  = bid & 511;
    const int b   = nt >> 7;
    const int y0  = nt & 127;
    const int m0  = mt << 7;

    __shared__ __align__(16) __hip_bfloat16 xs[2 * XSZ];

    // zero both xs buffers (border cols 0/129 stay zero forever)
    {
        int* z = (int*)xs;
        for (int j = tid; j < (2 * XSZ) / 2; j += 256) z[j] = 0;
    }

    // ---- B (X) read offsets in LDS (element units), channel-slot swizzled ----
    int bOff[4][3];
    #pragma unroll
    for (int ni = 0; ni < 4; ++ni)
        #pragma unroll
        for (int kx = 0; kx < 3; ++kx) {
            int colL = wn * 64 + ni * 16 + lr + kx;
            bOff[ni][kx] = colL * 32 + 8 * (q ^ ((colL >> 1) & 3));
        }

    // ---- A per-lane global addresses (fragment = 8 contiguous bf16) ----
    const __hip_bfloat16* aAddr[4];
    #pragma unroll
    for (int mi = 0; mi < 4; ++mi) {
        int row = m0 + wm * 64 + mi * 16 + lr;
        aAddr[mi] = rwb + (size_t)row * (KTAPS * CIN) + q * 8;
    }

    // ---- X staging: 6 loads cover 3 rows x 128 cols x 32 ch ----
    const __hip_bfloat16* srcX[6];
    int dstX[6];
    #pragma unroll
    for (int it = 0; it < 6; ++it) {
        int wt = it * 4 + w;
        int rr = wt >> 3, cg = (wt & 7) * 16;
        int gy = y0 - 1 + rr;
        size_t rowIdx = ((unsigned)gy < (unsigned)HH) ? (size_t)(b * HH + gy)
                                                      : (size_t)(BB * HH);
        int gx = cg + (lane >> 2);
        int colL = gx + 1;
        dstX[it] = (rr * 130 + 1 + cg) * 32;
        srcX[it] = xb + (rowIdx * WW + gx) * CIN + 8 * ((lane & 3) ^ ((colL >> 1) & 3));
    }

    f32x4 acc[4][4];
    #pragma unroll
    for (int mi = 0; mi < 4; ++mi)
        #pragma unroll
        for (int ni = 0; ni < 4; ++ni) {
            f32x4 z = {0.f, 0.f, 0.f, 0.f};
            acc[mi][ni] = z;
        }

    __syncthreads();   // zeroing complete before async loads land

    // prologue: X(chunk0) -> xs buf0; prefetch A(c0,t0)->a0, A(c0,t1)->a1
    #pragma unroll
    for (int j = 0; j < 6; ++j) g2l16(xs + dstX[j], srcX[j]);

    bf16x8 a0[4], a1[4], a2[4];
    #pragma unroll
    for (int mi = 0; mi < 4; ++mi) a0[mi] = *(const bf16x8*)(aAddr[mi]);
    #pragma unroll
    for (int mi = 0; mi < 4; ++mi) a1[mi] = *(const bf16x8*)(aAddr[mi] + CIN);

    __syncthreads();   // X chunk0 ready

// ---- one tap: prefetch A(+2) into ATGT; optionally stage X(c+1); ds_read B;
//      16 MFMA with ACUR. All buffer indices compile-time (rule #20).
#define TAP(P, ACUR, ATGT, DOA, AOFS, ISSX)                                    \
  {                                                                            \
    if (DOA) {                                                                 \
      _Pragma("unroll")                                                        \
      for (int mi = 0; mi < 4; ++mi)                                           \
        ATGT[mi] = *(const bf16x8*)(aAddr[mi] + (AOFS));                       \
    }                                                                          \
    if (ISSX) {                                                                \
      const int j0 = 2 * ((P) - 2);                                            \
      g2l16(xsW + dstX[j0],     srcX[j0]     + i1);                            \
      g2l16(xsW + dstX[j0 + 1], srcX[j0 + 1] + i1);                            \
    }                                                                          \
    bf16x8 bfv[4];                                                             \
    const __hip_bfloat16* br = xsR + (((P) / 3) * (130 * 32));                 \
    _Pragma("unroll")                                                          \
    for (int ni = 0; ni < 4; ++ni)                                             \
        bfv[ni] = *(const bf16x8*)(br + bOff[ni][(P) % 3]);                    \
    __builtin_amdgcn_s_setprio(1);                                             \
    _Pragma("unroll")                                                          \
    for (int mi = 0; mi < 4; ++mi)                                             \
        _Pragma("unroll")                                                      \
        for (int ni = 0; ni < 4; ++ni)                                         \
            acc[mi][ni] = __builtin_amdgcn_mfma_f32_16x16x32_bf16(             \
                ACUR[mi], bfv[ni], acc[mi][ni], 0, 0, 0);                      \
    __builtin_amdgcn_s_setprio(0);                                             \
  }

// cur = t%3, prefetch target = (t+2)%3. Taps 7,8 prefetch next chunk t0,t1
// (skip on last chunk). X(c+1) staged at taps 2,3,4 (skip on last chunk).
#define CHUNK(LASTC)                                                           \
  {                                                                            \
    const int i0 = c * 32;                                                     \
    const int i1 = i0 + 32;                                                    \
    const __hip_bfloat16* xsR = xs + (c & 1) * XSZ;                            \
    __hip_bfloat16* xsW = xs + ((c + 1) & 1) * XSZ;                            \
    (void)xsW; (void)i1;                                                       \
    TAP(0, a0, a2, 1, 2 * CIN + i0, 0)                                         \
    TAP(1, a1, a0, 1, 3 * CIN + i0, 0)                                         \
    TAP(2, a2, a1, 1, 4 * CIN + i0, !(LASTC))                                  \
    TAP(3, a0, a2, 1, 5 * CIN + i0, !(LASTC))                                  \
    TAP(4, a1, a0, 1, 6 * CIN + i0, !(LASTC))                                  \
    TAP(5, a2, a1, 1, 7 * CIN + i0, 0)                                         \
    TAP(6, a0, a2, 1, 8 * CIN + i0, 0)                                         \
    TAP(7, a1, a0, !(LASTC), 0 * CIN + i1, 0)                                  \
    TAP(8, a2, a1, !(LASTC), 1 * CIN + i1, 0)                                  \
    if (!(LASTC)) __syncthreads();                                             \
  }

    for (int c = 0; c < 7; ++c) CHUNK(0)
    { const int c = 7; CHUNK(1) }

#undef TAP
#undef CHUNK

    // epilogue: max over 8 rotations (4 regs + quarter-swap), write fp32
    const int oBase = (m0 + wm * 64) >> 3;
    #pragma unroll
    for (int mi = 0; mi < 4; ++mi) {
        #pragma unroll
        for (int ni = 0; ni < 4; ++ni) {
            f32x4 a4 = acc[mi][ni];
            float v = fmaxf(fmaxf(a4[0], a4[1]), fmaxf(a4[2], a4[3]));
            v = fmaxf(v, __shfl_xor(v, 16));
            if ((q & 1) == 0) {
                int o = oBase + mi * 2 + (q >> 1);
                int xcol = wn * 64 + ni * 16 + lr;
                out[(((size_t)(b * COUT + o)) * HH + y0) * WW + xcol] = v;
            }
        }
    }
}

// ===========================================================================
// Fallback fp32 path (round-0, known-correct) in case ws is too small.
// ===========================================================================
__global__ void rotate_weights_kernel(const float* __restrict__ w,
                                      float* __restrict__ rw,
                                      int r0, int rcount) {
    int idx = blockIdx.x * blockDim.x + threadIdx.x;
    int total = COUT * CIN * rcount;
    if (idx >= total) return;
    int rr = idx % rcount;
    int ii = (idx / rcount) % CIN;
    int oo = idx / (rcount * CIN);
    int r  = r0 + rr;
    float ang = 6.283185307179586f * (float)r / 8.0f;
    float cs = cosf(ang), sn = sinf(ang);
    const float* wp = w  + ((size_t)oo * CIN + ii) * 9;
    float*       op = rw + (((size_t)oo * CIN + ii) * rcount + rr) * 9;
    #pragma unroll
    for (int ky = 0; ky < 3; ++ky)
        #pragma unroll
        for (int kx = 0; kx < 3; ++kx) {
            float yg = (2.0f * ky + 1.0f) / 3.0f - 1.0f;
            float xg = (2.0f * kx + 1.0f) / 3.0f - 1.0f;
            float xsf = cs * xg - sn * yg;
            float ysf = sn * xg + cs * yg;
            float ix = ((xsf + 1.0f) * 3.0f - 1.0f) * 0.5f;
            float iy = ((ysf + 1.0f) * 3.0f - 1.0f) * 0.5f;
            float ix0f = floorf(ix), iy0f = floorf(iy);
            float wx1 = ix - ix0f,  wy1 = iy - iy0f;
            float wx0 = 1.0f - wx1, wy0 = 1.0f - wy1;
            int ix0 = (int)ix0f, iy0 = (int)iy0f;
            int ix1 = ix0 + 1,   iy1 = iy0 + 1;
            float acc = 0.0f;
            if (iy0 >= 0 && iy0 < 3 && ix0 >= 0 && ix0 < 3) acc += wp[iy0*3+ix0]*(wy0*wx0);
            if (iy0 >= 0 && iy0 < 3 && ix1 >= 0 && ix1 < 3) acc += wp[iy0*3+ix1]*(wy0*wx1);
            if (iy1 >= 0 && iy1 < 3 && ix0 >= 0 && ix0 < 3) acc += wp[iy1*3+ix0]*(wy1*wx0);
            if (iy1 >= 0 && iy1 < 3 && ix1 >= 0 && ix1 < 3) acc += wp[iy1*3+ix1]*(wy1*wx1);
            op[ky * 3 + kx] = acc;
        }
}

template <int RCOUNT>
__global__ __launch_bounds__(256)
void rotconv_max_kernel(const float* __restrict__ x,
                        const float* __restrict__ rw,
                        float* __restrict__ out,
                        int first) {
    const int tid = threadIdx.x;
    const int tx = tid & 15;
    const int ty = tid >> 4;
    const int x0 = blockIdx.x * 32;
    const int y0 = blockIdx.y * 32;
    const int o  = blockIdx.z % COUT;
    const int b  = blockIdx.z / COUT;
    __shared__ float xsm[34][36];
    float acc[RCOUNT][2][2];
    #pragma unroll
    for (int r = 0; r < RCOUNT; ++r)
        #pragma unroll
        for (int py = 0; py < 2; ++py)
            #pragma unroll
            for (int px = 0; px < 2; ++px) acc[r][py][px] = 0.0f;
    for (int i = 0; i < CIN; ++i) {
        __syncthreads();
        const float* xp = x + ((size_t)(b * CIN + i)) * (HH * WW);
        for (int idx = tid; idx < 34 * 34; idx += 256) {
            int row = idx / 34, col = idx - row * 34;
            int gy = y0 - 1 + row, gx = x0 - 1 + col;
            float v = 0.0f;
            if (gy >= 0 && gy < HH && gx >= 0 && gx < WW) v = xp[gy * WW + gx];
            xsm[row][col] = v;
        }
        __syncthreads();
        float xv[4][4];
        #pragma unroll
        for (int ry = 0; ry < 4; ++ry)
            #pragma unroll
            for (int cx = 0; cx < 4; ++cx) xv[ry][cx] = xsm[ty*2+ry][tx*2+cx];
        const float* wp = rw + ((size_t)(o * CIN + i)) * (RCOUNT * 9);
        #pragma unroll
        for (int r = 0; r < RCOUNT; ++r) {
            float wv[9];
            #pragma unroll
            for (int t2 = 0; t2 < 9; ++t2) wv[t2] = wp[r * 9 + t2];
            #pragma unroll
            for (int py = 0; py < 2; ++py)
                #pragma unroll
                for (int px = 0; px < 2; ++px) {
                    float a = acc[r][py][px];
                    #pragma unroll
                    for (int ky = 0; ky < 3; ++ky)
                        #pragma unroll
                        for (int kx = 0; kx < 3; ++kx)
                            a += xv[py+ky][px+kx] * wv[ky*3+kx];
                    acc[r][py][px] = a;
                }
        }
    }
    #pragma unroll
    for (int py = 0; py < 2; ++py)
        #pragma unroll
        for (int px = 0; px < 2; ++px) {
            float m = acc[0][py][px];
            #pragma unroll
            for (int r = 1; r < RCOUNT; ++r) m = fmaxf(m, acc[r][py][px]);
            int oy = y0 + ty * 2 + py;
            int ox = x0 + tx * 2 + px;
            float* op = out + (((size_t)(b * COUT + o)) * HH + oy) * WW + ox;
            if (first) *op = m;
            else       *op = fmaxf(*op, m);
        }
}

// ===========================================================================
extern "C" void kernel_launch(void* const* d_in, const int* in_sizes, int n_in,
                              void* d_out, int out_size, void* d_ws, size_t ws_size,
                              hipStream_t stream) {
    const float* x = (const float*)d_in[0];
    const float* w = (const float*)d_in[1];
    float* out = (float*)d_out;

    const size_t xbBytes = ((size_t)BB * HH * WW + WW) * CIN * sizeof(__hip_bfloat16); // +1 zero row
    const size_t rwBytes = (size_t)MTOT * KTAPS * CIN * sizeof(__hip_bfloat16);

    if (ws_size >= xbBytes + rwBytes) {
        __hip_bfloat16* xbuf = (__hip_bfloat16*)d_ws;
        __hip_bfloat16* rwb  = (__hip_bfloat16*)((char*)d_ws + xbBytes);

        to_nhwc_bf16<<<dim3((HH * WW) / 32, CIN / 32, BB), 256, 0, stream>>>(x, xbuf);
        zero_guard_row<<<(WW * CIN) / 256, 256, 0, stream>>>(xbuf);
        rotate_weights_bf16<<<MTOT, 256, 0, stream>>>(w, rwb);
        rotconv_mfma_kernel<<<16 * 512, 256, 0, stream>>>(xbuf, rwb, out);
        return;
    }

    // ---- fallback fp32 path ----
    float* rw = (float*)d_ws;
    int chunk = 8;
    while (chunk > 1 && (size_t)COUT * CIN * chunk * 9 * sizeof(float) > ws_size)
        chunk >>= 1;
    int first = 1;
    for (int r0 = 0; r0 < R_TOTAL; r0 += chunk) {
        int rc = chunk;
        int total = COUT * CIN * rc;
        rotate_weights_kernel<<<(total + 255) / 256, 256, 0, stream>>>(w, rw, r0, rc);
        dim3 grid(WW / 32, HH / 32, BB * COUT);
        switch (rc) {
            case 8: rotconv_max_kernel<8><<<grid, 256, 0, stream>>>(x, rw, out, first); break;
            case 4: rotconv_max_kernel<4><<<grid, 256, 0, stream>>>(x, rw, out, first); break;
            case 2: rotconv_max_kernel<2><<<grid, 256, 0, stream>>>(x, rw, out, first); break;
            default: rotconv_max_kernel<1><<<grid, 256, 0, stream>>>(x, rw, out, first); break;
        }
        first = 0;
    }
}

// Round 5
// 587.047 us; speedup vs baseline: 1.9205x; 1.9205x over previous
//
#include <hip/hip_runtime.h>
#include <hip/hip_bf16.h>
#include <math.h>

typedef __attribute__((ext_vector_type(8))) short bf16x8;
typedef __attribute__((ext_vector_type(4))) float f32x4;

#define R_TOTAL 8
#define CIN     256
#define COUT    256
#define HH      128
#define WW      128
#define BB      4
#define MTOT    (COUT * R_TOTAL)   // 2048
#define KTAPS   9

#define XROWS 4
#define XSZ   (XROWS * 130 * 32)   // 16640 elems per X buffer (33.3 KB)
#define ABUF  (128 * 32)           // 4096 elems per A buffer (8 KB)

// ---------------------------------------------------------------------------
// async global->LDS, 16B per lane (lane l lands at base + l*16).
// ---------------------------------------------------------------------------
__device__ __forceinline__ void g2l16(void* lds, const void* g) {
    __builtin_amdgcn_global_load_lds(
        (const __attribute__((address_space(1))) unsigned int*)g,
        (__attribute__((address_space(3))) unsigned int*)lds,
        16, 0, 0);
}

// ---------------------------------------------------------------------------
// x (B,C,H,W) fp32 -> xb (B,H,W,C) bf16 (+ one appended zero row).
// ---------------------------------------------------------------------------
__global__ __launch_bounds__(256)
void to_nhwc_bf16(const float* __restrict__ x, __hip_bfloat16* __restrict__ xb) {
    __shared__ __hip_bfloat16 t[32][33];
    const int b  = blockIdx.z;
    const int c0 = blockIdx.y * 32;
    const int p0 = blockIdx.x * 32;
    const int tx = threadIdx.x & 31;
    const int ty = threadIdx.x >> 5;
    const float* xp = x + (size_t)b * CIN * (HH * WW);
    #pragma unroll
    for (int j = 0; j < 4; ++j) {
        int c = ty * 4 + j;
        t[c][tx] = __float2bfloat16(xp[(size_t)(c0 + c) * (HH * WW) + p0 + tx]);
    }
    __syncthreads();
    __hip_bfloat16* op = xb + ((size_t)b * (HH * WW) + p0) * CIN + c0;
    #pragma unroll
    for (int j = 0; j < 4; ++j) {
        int p = ty * 4 + j;
        op[(size_t)p * CIN + tx] = t[tx][p];
    }
}

__global__ __launch_bounds__(256)
void zero_guard_row(__hip_bfloat16* __restrict__ xb) {
    size_t base = (size_t)BB * HH * WW * CIN;
    int i = blockIdx.x * 256 + threadIdx.x;
    xb[base + i] = __float2bfloat16(0.0f);
}

// ---------------------------------------------------------------------------
// Rotate weights (fp32 math == jax affine_grid/grid_sample, align_corners=F,
// zero pad) -> rwb[m][tap][i] bf16, m = o*8 + r.
// ---------------------------------------------------------------------------
__global__ __launch_bounds__(256)
void rotate_weights_bf16(const float* __restrict__ w, __hip_bfloat16* __restrict__ rwb) {
    const int i = threadIdx.x;
    const int m = blockIdx.x;
    const int o = m >> 3, r = m & 7;

    float ang = 6.283185307179586f * (float)r / 8.0f;
    float cs = cosf(ang), sn = sinf(ang);

    const float* wp = w + ((size_t)o * CIN + i) * 9;
    __hip_bfloat16* op = rwb + (size_t)m * (KTAPS * CIN) + i;

    #pragma unroll
    for (int ky = 0; ky < 3; ++ky) {
        #pragma unroll
        for (int kx = 0; kx < 3; ++kx) {
            float yg = (2.0f * (float)ky + 1.0f) / 3.0f - 1.0f;
            float xg = (2.0f * (float)kx + 1.0f) / 3.0f - 1.0f;
            float xsf = cs * xg - sn * yg;
            float ysf = sn * xg + cs * yg;
            float ix = ((xsf + 1.0f) * 3.0f - 1.0f) * 0.5f;
            float iy = ((ysf + 1.0f) * 3.0f - 1.0f) * 0.5f;
            float ix0f = floorf(ix), iy0f = floorf(iy);
            float wx1 = ix - ix0f,  wy1 = iy - iy0f;
            float wx0 = 1.0f - wx1, wy0 = 1.0f - wy1;
            int ix0 = (int)ix0f, iy0 = (int)iy0f;
            int ix1 = ix0 + 1,   iy1 = iy0 + 1;
            float acc = 0.0f;
            if (iy0 >= 0 && iy0 < 3 && ix0 >= 0 && ix0 < 3) acc += wp[iy0*3+ix0] * (wy0*wx0);
            if (iy0 >= 0 && iy0 < 3 && ix1 >= 0 && ix1 < 3) acc += wp[iy0*3+ix1] * (wy0*wx1);
            if (iy1 >= 0 && iy1 < 3 && ix0 >= 0 && ix0 < 3) acc += wp[iy1*3+ix0] * (wy1*wx0);
            if (iy1 >= 0 && iy1 < 3 && ix1 >= 0 && ix1 < 3) acc += wp[iy1*3+ix1] * (wy1*wx1);
            op[(ky * 3 + kx) * CIN] = __float2bfloat16(acc);
        }
    }
}

// ---------------------------------------------------------------------------
// Main MFMA conv: 512 threads = 8 waves (2M x 4N), block tile 128M x 256N
// (two consecutive image rows). K = 8 chunks(32ch) x 9 taps, counted-vmcnt
// schedule: one raw s_barrier per tap, never drain vmcnt to 0 in-loop.
// A: 4-buffered LDS (prefetch distance 2 taps, 1 g2l/wave/tap).
// X: double-buffered 4-row window, staged 1 g2l/wave/tap at taps 2..5.
// ---------------------------------------------------------------------------
__global__ __launch_bounds__(512)
void rotconv_mfma_kernel(const __hip_bfloat16* __restrict__ xb,
                         const __hip_bfloat16* __restrict__ rwb,
                         float* __restrict__ out) {
    const int tid  = threadIdx.x;
    const int lane = tid & 63;
    const int w    = tid >> 6;        // 0..7
    const int wm   = w >> 2;          // 0..1
    const int wn   = w & 3;           // 0..3
    const int q    = lane >> 4, lr = lane & 15;

    // bijective XCD swizzle (4096 % 8 == 0): each XCD owns 2 m-panels
    const int bid = (blockIdx.x & 7) * 512 + (blockIdx.x >> 3);
    const int mt  = bid >> 8;         // 0..15
    const int nt  = bid & 255;        // 0..255
    const int b   = nt >> 6;          // 0..3
    const int y0  = (nt & 63) * 2;    // 0..126
    const int m0  = mt << 7;

    __shared__ __align__(16) __hip_bfloat16 xs[2 * XSZ];
    __shared__ __align__(16) __hip_bfloat16 As[4 * ABUF];

    // zero halo columns (colL = 0 and 129): 2 bufs x 4 rows x 2 cols x 32 ch = 512
    {
        int bufi = tid >> 8;
        int rem  = tid & 255;
        int row = rem >> 6; int colsel = (rem >> 5) & 1; int ch = rem & 31;
        int colL = colsel ? 129 : 0;
        xs[bufi * XSZ + (row * 130 + colL) * 32 + ch] = __float2bfloat16(0.0f);
    }

    // ---- A read offsets (element units), slot-swizzled ----
    int aOff[4];
    #pragma unroll
    for (int mi = 0; mi < 4; ++mi) {
        int row = wm * 64 + mi * 16 + lr;
        aOff[mi] = row * 32 + 8 * (q ^ ((row >> 1) & 3));
    }
    // ---- B read offsets: pixel p = wn*64 + ni*16 + lr -> (imgrow, col) ----
    int bOff[4][3];
    #pragma unroll
    for (int ni = 0; ni < 4; ++ni) {
        int pbase = wn * 64 + ni * 16;
        int ir = pbase >> 7;                 // 0 or 1 (constant over lr)
        int col = (pbase & 127) + lr;        // 0..127
        #pragma unroll
        for (int kx = 0; kx < 3; ++kx) {
            int colL = col + kx;             // 0..129
            bOff[ni][kx] = (ir * 130 + colL) * 32 + 8 * (q ^ ((colL >> 1) & 3));
        }
    }

    // ---- A staging: wave w covers rows w*16..w*16+15 (1 g2l per wave) ----
    const int arow = w * 16 + (lane >> 2);
    const int dstA = (w * 16) * 32;                        // wave-uniform
    const __hip_bfloat16* srcA =
        rwb + (size_t)(m0 + arow) * (KTAPS * CIN) + 8 * ((lane & 3) ^ ((arow >> 1) & 3));

    // ---- X staging: 4 insts/wave cover 4 rows x 128 cols x 32 ch ----
    const __hip_bfloat16* srcX[4];
    int dstX[4];
    #pragma unroll
    for (int j = 0; j < 4; ++j) {
        int id = j * 8 + w;                  // 0..31
        int row = id >> 3;                   // 0..3 (window row)
        int cg  = (id & 7) * 16;             // col group base
        int gy = y0 - 1 + row;
        size_t rowIdx = ((unsigned)gy < (unsigned)HH) ? (size_t)(b * HH + gy)
                                                      : (size_t)(BB * HH);
        int gx = cg + (lane >> 2);
        int colL = gx + 1;
        dstX[j] = (row * 130 + 1 + cg) * 32;               // wave-uniform
        srcX[j] = xb + (rowIdx * WW + gx) * CIN + 8 * ((lane & 3) ^ ((colL >> 1) & 3));
    }

    f32x4 acc[4][4];
    #pragma unroll
    for (int mi = 0; mi < 4; ++mi)
        #pragma unroll
        for (int ni = 0; ni < 4; ++ni) {
            f32x4 z = {0.f, 0.f, 0.f, 0.f};
            acc[mi][ni] = z;
        }

    __syncthreads();   // halo zeros visible

    // prologue: X(chunk0), then A(k-step0), A(k-step1) — order pinned
    #pragma unroll
    for (int j = 0; j < 4; ++j) g2l16(xs + dstX[j], srcX[j]);
    __builtin_amdgcn_sched_barrier(0);
    g2l16(As + 0 * ABUF + dstA, srcA + 0 * CIN);
    __builtin_amdgcn_sched_barrier(0);
    g2l16(As + 1 * ABUF + dstA, srcA + 1 * CIN);

// ---- one tap (global k-step g = 9C+P): issue A(g+2) [+ X(c+1)], counted
//      wait, raw barrier, ds_read A/B, 16 MFMA. All indices compile-time.
#define TAP(C, P, NW, DOA, DOX)                                                \
  {                                                                            \
    if (DOA) {                                                                 \
      g2l16(As + ((9*(C)+(P)+2) & 3) * ABUF + dstA,                            \
            srcA + ((9*(C)+(P)+2) % 9) * CIN + ((9*(C)+(P)+2) / 9) * 32);      \
    }                                                                          \
    if (DOX) {                                                                 \
      g2l16(xs + (((C)+1) & 1) * XSZ + dstX[(P)-2],                            \
            srcX[(P)-2] + ((C)+1) * 32);                                       \
    }                                                                          \
    asm volatile("s_waitcnt vmcnt(%0)" :: "i"(NW) : "memory");                 \
    asm volatile("s_barrier" ::: "memory");                                    \
    {                                                                          \
      const __hip_bfloat16* ar = As + ((9*(C)+(P)) & 3) * ABUF;                \
      const __hip_bfloat16* br = xs + ((C) & 1) * XSZ + ((P)/3) * (130 * 32);  \
      bf16x8 af[4], bv[4];                                                     \
      _Pragma("unroll")                                                        \
      for (int mi = 0; mi < 4; ++mi) af[mi] = *(const bf16x8*)(ar + aOff[mi]); \
      _Pragma("unroll")                                                        \
      for (int ni = 0; ni < 4; ++ni)                                           \
          bv[ni] = *(const bf16x8*)(br + bOff[ni][(P) % 3]);                   \
      __builtin_amdgcn_s_setprio(1);                                           \
      _Pragma("unroll")                                                        \
      for (int mi = 0; mi < 4; ++mi)                                           \
          _Pragma("unroll")                                                    \
          for (int ni = 0; ni < 4; ++ni)                                       \
              acc[mi][ni] = __builtin_amdgcn_mfma_f32_16x16x32_bf16(           \
                  af[mi], bv[ni], acc[mi][ni], 0, 0, 0);                       \
      __builtin_amdgcn_s_setprio(0);                                           \
    }                                                                          \
  }

// order-robust vmcnt tables (min over both within-tap issue orders):
// steady/chunk0: [2,2,3,4,4,4,3,2,2]; last chunk: [2,2,2,2,2,2,2,1,0]
#define CHUNK_MID(C)                                                           \
    TAP(C, 0, 2, 1, 0) TAP(C, 1, 2, 1, 0) TAP(C, 2, 3, 1, 1)                   \
    TAP(C, 3, 4, 1, 1) TAP(C, 4, 4, 1, 1) TAP(C, 5, 4, 1, 1)                   \
    TAP(C, 6, 3, 1, 0) TAP(C, 7, 2, 1, 0) TAP(C, 8, 2, 1, 0)

    CHUNK_MID(0) CHUNK_MID(1) CHUNK_MID(2) CHUNK_MID(3)
    CHUNK_MID(4) CHUNK_MID(5) CHUNK_MID(6)
    TAP(7, 0, 2, 1, 0) TAP(7, 1, 2, 1, 0) TAP(7, 2, 2, 1, 0)
    TAP(7, 3, 2, 1, 0) TAP(7, 4, 2, 1, 0) TAP(7, 5, 2, 1, 0)
    TAP(7, 6, 2, 1, 0) TAP(7, 7, 1, 0, 0) TAP(7, 8, 0, 0, 0)

#undef TAP
#undef CHUNK_MID

    // epilogue: max over 8 rotations (4 regs + quarter-swap), write fp32
    const int oBase = (m0 + wm * 64) >> 3;
    #pragma unroll
    for (int mi = 0; mi < 4; ++mi) {
        #pragma unroll
        for (int ni = 0; ni < 4; ++ni) {
            f32x4 a4 = acc[mi][ni];
            float v = fmaxf(fmaxf(a4[0], a4[1]), fmaxf(a4[2], a4[3]));
            v = fmaxf(v, __shfl_xor(v, 16));
            if ((q & 1) == 0) {
                int o = oBase + mi * 2 + (q >> 1);
                int p = wn * 64 + ni * 16 + lr;
                int y = y0 + (p >> 7);
                int colc = p & 127;
                out[(((size_t)(b * COUT + o)) * HH + y) * WW + colc] = v;
            }
        }
    }
}

// ===========================================================================
// Fallback fp32 path (round-0, known-correct) in case ws is too small.
// ===========================================================================
__global__ void rotate_weights_kernel(const float* __restrict__ w,
                                      float* __restrict__ rw,
                                      int r0, int rcount) {
    int idx = blockIdx.x * blockDim.x + threadIdx.x;
    int total = COUT * CIN * rcount;
    if (idx >= total) return;
    int rr = idx % rcount;
    int ii = (idx / rcount) % CIN;
    int oo = idx / (rcount * CIN);
    int r  = r0 + rr;
    float ang = 6.283185307179586f * (float)r / 8.0f;
    float cs = cosf(ang), sn = sinf(ang);
    const float* wp = w  + ((size_t)oo * CIN + ii) * 9;
    float*       op = rw + (((size_t)oo * CIN + ii) * rcount + rr) * 9;
    #pragma unroll
    for (int ky = 0; ky < 3; ++ky)
        #pragma unroll
        for (int kx = 0; kx < 3; ++kx) {
            float yg = (2.0f * ky + 1.0f) / 3.0f - 1.0f;
            float xg = (2.0f * kx + 1.0f) / 3.0f - 1.0f;
            float xsf = cs * xg - sn * yg;
            float ysf = sn * xg + cs * yg;
            float ix = ((xsf + 1.0f) * 3.0f - 1.0f) * 0.5f;
            float iy = ((ysf + 1.0f) * 3.0f - 1.0f) * 0.5f;
            float ix0f = floorf(ix), iy0f = floorf(iy);
            float wx1 = ix - ix0f,  wy1 = iy - iy0f;
            float wx0 = 1.0f - wx1, wy0 = 1.0f - wy1;
            int ix0 = (int)ix0f, iy0 = (int)iy0f;
            int ix1 = ix0 + 1,   iy1 = iy0 + 1;
            float acc = 0.0f;
            if (iy0 >= 0 && iy0 < 3 && ix0 >= 0 && ix0 < 3) acc += wp[iy0*3+ix0]*(wy0*wx0);
            if (iy0 >= 0 && iy0 < 3 && ix1 >= 0 && ix1 < 3) acc += wp[iy0*3+ix1]*(wy0*wx1);
            if (iy1 >= 0 && iy1 < 3 && ix0 >= 0 && ix0 < 3) acc += wp[iy1*3+ix0]*(wy1*wx0);
            if (iy1 >= 0 && iy1 < 3 && ix1 >= 0 && ix1 < 3) acc += wp[iy1*3+ix1]*(wy1*wx1);
            op[ky * 3 + kx] = acc;
        }
}

template <int RCOUNT>
__global__ __launch_bounds__(256)
void rotconv_max_kernel(const float* __restrict__ x,
                        const float* __restrict__ rw,
                        float* __restrict__ out,
                        int first) {
    const int tid = threadIdx.x;
    const int tx = tid & 15;
    const int ty = tid >> 4;
    const int x0 = blockIdx.x * 32;
    const int y0 = blockIdx.y * 32;
    const int o  = blockIdx.z % COUT;
    const int b  = blockIdx.z / COUT;
    __shared__ float xsm[34][36];
    float acc[RCOUNT][2][2];
    #pragma unroll
    for (int r = 0; r < RCOUNT; ++r)
        #pragma unroll
        for (int py = 0; py < 2; ++py)
            #pragma unroll
            for (int px = 0; px < 2; ++px) acc[r][py][px] = 0.0f;
    for (int i = 0; i < CIN; ++i) {
        __syncthreads();
        const float* xp = x + ((size_t)(b * CIN + i)) * (HH * WW);
        for (int idx = tid; idx < 34 * 34; idx += 256) {
            int row = idx / 34, col = idx - row * 34;
            int gy = y0 - 1 + row, gx = x0 - 1 + col;
            float v = 0.0f;
            if (gy >= 0 && gy < HH && gx >= 0 && gx < WW) v = xp[gy * WW + gx];
            xsm[row][col] = v;
        }
        __syncthreads();
        float xv[4][4];
        #pragma unroll
        for (int ry = 0; ry < 4; ++ry)
            #pragma unroll
            for (int cx = 0; cx < 4; ++cx) xv[ry][cx] = xsm[ty*2+ry][tx*2+cx];
        const float* wp = rw + ((size_t)(o * CIN + i)) * (RCOUNT * 9);
        #pragma unroll
        for (int r = 0; r < RCOUNT; ++r) {
            float wv[9];
            #pragma unroll
            for (int t2 = 0; t2 < 9; ++t2) wv[t2] = wp[r * 9 + t2];
            #pragma unroll
            for (int py = 0; py < 2; ++py)
                #pragma unroll
                for (int px = 0; px < 2; ++px) {
                    float a = acc[r][py][px];
                    #pragma unroll
                    for (int ky = 0; ky < 3; ++ky)
                        #pragma unroll
                        for (int kx = 0; kx < 3; ++kx)
                            a += xv[py+ky][px+kx] * wv[ky*3+kx];
                    acc[r][py][px] = a;
                }
        }
    }
    #pragma unroll
    for (int py = 0; py < 2; ++py)
        #pragma unroll
        for (int px = 0; px < 2; ++px) {
            float m = acc[0][py][px];
            #pragma unroll
            for (int r = 1; r < RCOUNT; ++r) m = fmaxf(m, acc[r][py][px]);
            int oy = y0 + ty * 2 + py;
            int ox = x0 + tx * 2 + px;
            float* op = out + (((size_t)(b * COUT + o)) * HH + oy) * WW + ox;
            if (first) *op = m;
            else       *op = fmaxf(*op, m);
        }
}

// ===========================================================================
extern "C" void kernel_launch(void* const* d_in, const int* in_sizes, int n_in,
                              void* d_out, int out_size, void* d_ws, size_t ws_size,
                              hipStream_t stream) {
    const float* x = (const float*)d_in[0];
    const float* w = (const float*)d_in[1];
    float* out = (float*)d_out;

    const size_t xbBytes = ((size_t)BB * HH * WW + WW) * CIN * sizeof(__hip_bfloat16); // +1 zero row
    const size_t rwBytes = (size_t)MTOT * KTAPS * CIN * sizeof(__hip_bfloat16);

    if (ws_size >= xbBytes + rwBytes) {
        __hip_bfloat16* xbuf = (__hip_bfloat16*)d_ws;
        __hip_bfloat16* rwb  = (__hip_bfloat16*)((char*)d_ws + xbBytes);

        to_nhwc_bf16<<<dim3((HH * WW) / 32, CIN / 32, BB), 256, 0, stream>>>(x, xbuf);
        zero_guard_row<<<(WW * CIN) / 256, 256, 0, stream>>>(xbuf);
        rotate_weights_bf16<<<MTOT, 256, 0, stream>>>(w, rwb);
        rotconv_mfma_kernel<<<4096, 512, 0, stream>>>(xbuf, rwb, out);
        return;
    }

    // ---- fallback fp32 path ----
    float* rw = (float*)d_ws;
    int chunk = 8;
    while (chunk > 1 && (size_t)COUT * CIN * chunk * 9 * sizeof(float) > ws_size)
        chunk >>= 1;
    int first = 1;
    for (int r0 = 0; r0 < R_TOTAL; r0 += chunk) {
        int rc = chunk;
        int total = COUT * CIN * rc;
        rotate_weights_kernel<<<(total + 255) / 256, 256, 0, stream>>>(w, rw, r0, rc);
        dim3 grid(WW / 32, HH / 32, BB * COUT);
        switch (rc) {
            case 8: rotconv_max_kernel<8><<<grid, 256, 0, stream>>>(x, rw, out, first); break;
            case 4: rotconv_max_kernel<4><<<grid, 256, 0, stream>>>(x, rw, out, first); break;
            case 2: rotconv_max_kernel<2><<<grid, 256, 0, stream>>>(x, rw, out, first); break;
            default: rotconv_max_kernel<1><<<grid, 256, 0, stream>>>(x, rw, out, first); break;
        }
        first = 0;
    }
}